// Round 1
// baseline (68.011 us; speedup 1.0000x reference)
//
#include <hip/hip_runtime.h>

// Problem constants (from reference):
//   N=64, C=4, LPC=8, KPL=4, D=4096, BLOCK=C*LPC*KPL=128, P=3*BLOCK=384
// out[n,c,d] = sum_g amp[n,c,g] * exp(-0.5*(x[n,c,d]-mu[n,c,g])^2 / sigma[n,c,g]^2)
// with g ranging over the LPC*KPL = 32 gaussians of channel c.

#define NN   64
#define CC   4
#define GG   32        // LPC*KPL gaussians per (n,c)
#define DD   4096
#define PP   384       // network_outputs row length
#define TPB  256       // threads per block
#define EPT  4         // elements (floats) per thread -> one float4
// Each block covers TPB*EPT = 1024 contiguous d's of one (n,c) row.
// Grid = (DD/1024, NN*CC) = (4, 256).

__global__ __launch_bounds__(TPB) void gauss_mix_kernel(
    const float* __restrict__ x,
    const float* __restrict__ net,        // (N, P)
    const int*   __restrict__ amp_idx,    // (C, LPC, KPL) flat = C*32
    const int*   __restrict__ mu_idx,
    const int*   __restrict__ sigma_idx,
    float* __restrict__ out)
{
    __shared__ float s_amp[GG];
    __shared__ float s_mu[GG];
    __shared__ float s_sc[GG];   // -0.5*log2(e)/sigma^2

    const int row = blockIdx.y;          // n*C + c
    const int n   = row >> 2;            // / CC
    const int c   = row & (CC - 1);
    const int tid = threadIdx.x;

    if (tid < GG) {
        const int gi   = c * GG + tid;       // index into the (C,LPC,KPL) tables
        const int base = n * PP;
        const float a  = net[base + amp_idx[gi]];
        const float m  = net[base + mu_idx[gi]];
        const float s  = net[base + sigma_idx[gi]];
        s_amp[tid] = a;
        s_mu[tid]  = m;
        // exp(z) = exp2(z*log2e); fold -0.5*log2e into the per-gaussian scale.
        s_sc[tid]  = -0.72134752044f / (s * s);   // -0.5 * 1.4426950408889634
    }
    __syncthreads();

    const int d0 = blockIdx.x * (TPB * EPT) + tid * EPT;
    const size_t off = (size_t)row * DD + d0;

    const float4 xv = *(const float4*)(x + off);
    float4 acc = make_float4(0.f, 0.f, 0.f, 0.f);

    #pragma unroll
    for (int g = 0; g < GG; ++g) {
        const float m  = s_mu[g];    // broadcast LDS reads (conflict-free)
        const float sc = s_sc[g];
        const float a  = s_amp[g];
        const float t0 = xv.x - m;
        const float t1 = xv.y - m;
        const float t2 = xv.z - m;
        const float t3 = xv.w - m;
        acc.x = fmaf(a, __builtin_amdgcn_exp2f(t0 * t0 * sc), acc.x);
        acc.y = fmaf(a, __builtin_amdgcn_exp2f(t1 * t1 * sc), acc.y);
        acc.z = fmaf(a, __builtin_amdgcn_exp2f(t2 * t2 * sc), acc.z);
        acc.w = fmaf(a, __builtin_amdgcn_exp2f(t3 * t3 * sc), acc.w);
    }

    *(float4*)(out + off) = acc;
}

extern "C" void kernel_launch(void* const* d_in, const int* in_sizes, int n_in,
                              void* d_out, int out_size, void* d_ws, size_t ws_size,
                              hipStream_t stream)
{
    const float* x       = (const float*)d_in[0];   // (N, C, D)
    const float* net     = (const float*)d_in[1];   // (N, P)
    const int*   amp_idx = (const int*)d_in[2];     // (C, LPC, KPL)
    const int*   mu_idx  = (const int*)d_in[3];
    const int*   sig_idx = (const int*)d_in[4];
    float*       out     = (float*)d_out;           // (N, C, D)

    dim3 grid(DD / (TPB * EPT), NN * CC);
    dim3 block(TPB);
    gauss_mix_kernel<<<grid, block, 0, stream>>>(x, net, amp_idx, mu_idx, sig_idx, out);
}

// Round 2
// 67.167 us; speedup vs baseline: 1.0126x; 1.0126x over previous
//
#include <hip/hip_runtime.h>

// Problem constants (from reference):
//   N=64, C=4, LPC=8, KPL=4, D=4096, BLOCK=C*LPC*KPL=128, P=3*BLOCK=384
// out[n,c,d] = sum_g amp[n,c,g] * exp(-0.5*(x[n,c,d]-mu[n,c,g])^2 / sigma[n,c,g]^2)
// g ranges over the LPC*KPL = 32 gaussians of channel c.
//
// Inner-loop formulation (saves 1 VALU op/gaussian-element vs naive):
//   exp(-0.5 (x-m)^2 / s^2) = exp2( -((x*r + mmr))^2 ),
//   r = sqrt(0.5*log2(e))/s,  mmr = -m*r.
// Per gaussian-element: v_fma (u), v_mul (u*u), v_exp (neg input mod), v_fma (acc).

#define NN   64
#define CC   4
#define GG   32        // LPC*KPL gaussians per (n,c)
#define DD   4096
#define PP   384       // network_outputs row length
#define TPB  256       // threads per block
#define EPT  4         // one float4 per thread
// Each block covers TPB*EPT = 1024 contiguous d's of one (n,c) row.
// Grid = (DD/1024, NN*CC) = (4, 256) = 1024 blocks -> 4 blocks/CU.

__global__ __launch_bounds__(TPB) void gauss_mix_kernel(
    const float* __restrict__ x,
    const float* __restrict__ net,        // (N, P)
    const int*   __restrict__ amp_idx,    // (C, LPC, KPL) flat = C*32
    const int*   __restrict__ mu_idx,
    const int*   __restrict__ sigma_idx,
    float* __restrict__ out)
{
    __shared__ float s_amp[GG];
    __shared__ float s_r[GG];    // sqrt(0.5*log2e)/sigma
    __shared__ float s_mmr[GG];  // -mu * r

    const int row = blockIdx.y;          // n*C + c
    const int n   = row >> 2;            // / CC
    const int c   = row & (CC - 1);
    const int tid = threadIdx.x;

    if (tid < GG) {
        const int gi   = c * GG + tid;
        const int base = n * PP;
        const float a  = net[base + amp_idx[gi]];
        const float m  = net[base + mu_idx[gi]];
        const float s  = net[base + sigma_idx[gi]];
        const float r  = 0.84932178f / s;   // sqrt(0.5 * 1.4426950408889634)
        s_amp[tid] = a;
        s_r[tid]   = r;
        s_mmr[tid] = -m * r;
    }
    __syncthreads();

    const int d0 = blockIdx.x * (TPB * EPT) + tid * EPT;
    const size_t off = (size_t)row * DD + d0;

    const float4 xv = *(const float4*)(x + off);
    float4 acc = make_float4(0.f, 0.f, 0.f, 0.f);

    #pragma unroll
    for (int g = 0; g < GG; ++g) {
        const float r   = s_r[g];     // broadcast LDS reads (conflict-free)
        const float mmr = s_mmr[g];
        const float a   = s_amp[g];
        const float u0 = fmaf(xv.x, r, mmr);
        const float u1 = fmaf(xv.y, r, mmr);
        const float u2 = fmaf(xv.z, r, mmr);
        const float u3 = fmaf(xv.w, r, mmr);
        acc.x = fmaf(a, __builtin_amdgcn_exp2f(-(u0 * u0)), acc.x);
        acc.y = fmaf(a, __builtin_amdgcn_exp2f(-(u1 * u1)), acc.y);
        acc.z = fmaf(a, __builtin_amdgcn_exp2f(-(u2 * u2)), acc.z);
        acc.w = fmaf(a, __builtin_amdgcn_exp2f(-(u3 * u3)), acc.w);
    }

    *(float4*)(out + off) = acc;
}

extern "C" void kernel_launch(void* const* d_in, const int* in_sizes, int n_in,
                              void* d_out, int out_size, void* d_ws, size_t ws_size,
                              hipStream_t stream)
{
    const float* x       = (const float*)d_in[0];   // (N, C, D)
    const float* net     = (const float*)d_in[1];   // (N, P)
    const int*   amp_idx = (const int*)d_in[2];     // (C, LPC, KPL)
    const int*   mu_idx  = (const int*)d_in[3];
    const int*   sig_idx = (const int*)d_in[4];
    float*       out     = (float*)d_out;           // (N, C, D)

    dim3 grid(DD / (TPB * EPT), NN * CC);
    dim3 block(TPB);
    gauss_mix_kernel<<<grid, block, 0, stream>>>(x, net, amp_idx, mu_idx, sig_idx, out);
}